// Round 1
// baseline (325.589 us; speedup 1.0000x reference)
//
#include <hip/hip_runtime.h>

#define N_NODES 500000
#define K_NB 16
#define F_IN 7
#define F_HID 40
#define F_OUT 3

// Thread-per-node. Layer-2 commuted past the k-mean: y = (sum_k relu(m_k@W1+b1))@W2/16 + b2.
// W1 packed transposed in LDS as [h][8] = {W1[0..6][h], b1[h]} -> two b128 broadcast reads per h.
// W2 packed as [h][4] = {W2[h][0..2], 0} -> one b128 broadcast read per h.
__global__ __launch_bounds__(256) void aggre_kernel(
    const float* __restrict__ mailbox,
    const float* __restrict__ W1,
    const float* __restrict__ b1,
    const float* __restrict__ W2,
    const float* __restrict__ b2,
    float* __restrict__ out)
{
    __shared__ float4 w1lds[F_HID * 2];  // [h*2+0] = W1[0..3][h]; [h*2+1] = {W1[4..6][h], b1[h]}
    __shared__ float4 w2lds[F_HID];      // [h] = {W2[h][0..2], 0}

    const int t = threadIdx.x;
    if (t < F_HID * 2) {          // 80 threads fill w1lds
        const int h = t >> 1;
        float4 v;
        if ((t & 1) == 0) {
            v.x = W1[0 * F_HID + h]; v.y = W1[1 * F_HID + h];
            v.z = W1[2 * F_HID + h]; v.w = W1[3 * F_HID + h];
        } else {
            v.x = W1[4 * F_HID + h]; v.y = W1[5 * F_HID + h];
            v.z = W1[6 * F_HID + h]; v.w = b1[h];
        }
        w1lds[t] = v;
    } else if (t < F_HID * 2 + F_HID) {  // 40 threads fill w2lds
        const int h = t - F_HID * 2;
        float4 v;
        v.x = W2[h * F_OUT + 0];
        v.y = W2[h * F_OUT + 1];
        v.z = W2[h * F_OUT + 2];
        v.w = 0.0f;
        w2lds[h] = v;
    }
    __syncthreads();

    const int n = blockIdx.x * blockDim.x + threadIdx.x;
    if (n >= N_NODES) return;

    // Load this node's 16x7 mailbox block: 112 floats = 28 float4 (448 B, 16B-aligned).
    float4 mb[28];
    const float4* __restrict__ src =
        (const float4*)(mailbox + (size_t)n * (K_NB * F_IN));
    #pragma unroll
    for (int i = 0; i < 28; ++i) mb[i] = src[i];
    const float* m = (const float*)mb;

    float a0 = 0.0f, a1 = 0.0f, a2 = 0.0f;

    for (int h = 0; h < F_HID; ++h) {
        const float4 wa = w1lds[h * 2 + 0];
        const float4 wb = w1lds[h * 2 + 1];  // wb.w = b1[h]
        float sh = 0.0f;
        #pragma unroll
        for (int k = 0; k < K_NB; ++k) {
            const float* mk = m + k * F_IN;
            float acc = wb.w;
            acc = fmaf(mk[0], wa.x, acc);
            acc = fmaf(mk[1], wa.y, acc);
            acc = fmaf(mk[2], wa.z, acc);
            acc = fmaf(mk[3], wa.w, acc);
            acc = fmaf(mk[4], wb.x, acc);
            acc = fmaf(mk[5], wb.y, acc);
            acc = fmaf(mk[6], wb.z, acc);
            sh += fmaxf(acc, 0.0f);
        }
        const float4 w2v = w2lds[h];
        a0 = fmaf(sh, w2v.x, a0);
        a1 = fmaf(sh, w2v.y, a1);
        a2 = fmaf(sh, w2v.z, a2);
    }

    const float inv = 1.0f / (float)K_NB;
    float* __restrict__ op = out + (size_t)n * F_OUT;
    op[0] = fmaf(a0, inv, b2[0]);
    op[1] = fmaf(a1, inv, b2[1]);
    op[2] = fmaf(a2, inv, b2[2]);
}

extern "C" void kernel_launch(void* const* d_in, const int* in_sizes, int n_in,
                              void* d_out, int out_size, void* d_ws, size_t ws_size,
                              hipStream_t stream) {
    const float* mailbox = (const float*)d_in[0];
    const float* W1      = (const float*)d_in[1];
    const float* b1      = (const float*)d_in[2];
    const float* W2      = (const float*)d_in[3];
    const float* b2      = (const float*)d_in[4];
    float* out = (float*)d_out;

    const int threads = 256;
    const int blocks = (N_NODES + threads - 1) / threads;
    aggre_kernel<<<blocks, threads, 0, stream>>>(mailbox, W1, b1, W2, b2, out);
}